// Round 4
// baseline (1248.479 us; speedup 1.0000x reference)
//
#include <hip/hip_runtime.h>
#include <hip/hip_bf16.h>

#define NN 49152
#define GG 1024
#define EE 65536
#define ETOT 196608
#define FF 384
#define NEG_SLOPE 0.2f

typedef __attribute__((ext_vector_type(8))) short bf16x8;
typedef __attribute__((ext_vector_type(4))) float f32x4;

__device__ __forceinline__ float wave_sum(float v) {
#pragma unroll
    for (int m = 32; m; m >>= 1) v += __shfl_xor(v, m);
    return v;
}
__device__ __forceinline__ unsigned short f2bf(float f) {
    __hip_bfloat16 b = __float2bfloat16(f);
    return *reinterpret_cast<unsigned short*>(&b);
}
__device__ __forceinline__ float bflo(unsigned u) { return __uint_as_float(u << 16); }
__device__ __forceinline__ float bfhi(unsigned u) { return __uint_as_float(u & 0xffff0000u); }

__device__ __forceinline__ void gload_lds16(const void* g, void* l) {
    __builtin_amdgcn_global_load_lds(
        (const __attribute__((address_space(1))) unsigned int*)g,
        (__attribute__((address_space(3))) unsigned int*)l, 16, 0, 0);
}

// ================= MFMA bf16 GEMM: C = act(A @ Bt^T + bias) =================
// Physical LDS convention: position (row, c) holds logical chunk c ^ ((row>>1)&3).
__device__ __forceinline__ int swz(int row, int c16) {
    return row * 64 + ((c16 ^ ((row >> 1) & 3)) << 4);
}

template <int ACT, bool ABF, bool OBF>
__global__ __launch_bounds__(256) void gemm_mfma(
    const void* __restrict__ Ag, int K,
    const unsigned short* __restrict__ Btg,
    const float* __restrict__ bias,
    void* __restrict__ Cg, int ldc,
    size_t bzs, size_t czs)
{
    __shared__ __align__(16) char As[8192];
    __shared__ __align__(16) char Bs[8192];
    const unsigned short* Bt = Btg + (size_t)blockIdx.z * bzs;
    int t = threadIdx.x;
    int bm = blockIdx.y << 7, bn = blockIdx.x << 7;
    int lane = t & 63, wid = t >> 6, wr = wid >> 1, wc = wid & 1;
    f32x4 acc[4][4] = {};
    int ktn = K >> 5;
    for (int kt = 0; kt < ktn; ++kt) {
        int k0 = kt << 5;
#pragma unroll
        for (int ii = 0; ii < 2; ++ii) {
            int id = t + (ii << 8);
            int row = id >> 2, c = id & 3;
            int csrc = c ^ ((row >> 1) & 3);  // pre-swizzled source chunk
            char* ldsbase = ((char*)0) + ((wid << 10) + (ii << 12));  // wave-uniform offset
            // A staging
            if (ABF) {
                const unsigned short* srcA = (const unsigned short*)Ag + (size_t)(bm + row) * K + k0 + csrc * 8;
                gload_lds16(srcA, As + (size_t)(ldsbase - (char*)0));
            } else {
                const float* srcA = (const float*)Ag + (size_t)(bm + row) * K + k0 + c * 8;
                float4 a0 = *(const float4*)srcA;
                float4 a1 = *(const float4*)(srcA + 4);
                union { unsigned short u[8]; int4 v; } P;
                P.u[0] = f2bf(a0.x); P.u[1] = f2bf(a0.y); P.u[2] = f2bf(a0.z); P.u[3] = f2bf(a0.w);
                P.u[4] = f2bf(a1.x); P.u[5] = f2bf(a1.y); P.u[6] = f2bf(a1.z); P.u[7] = f2bf(a1.w);
                *(int4*)(As + swz(row, c)) = P.v;
            }
            // B staging (always bf16, LDS-DMA)
            const unsigned short* srcB = Bt + (size_t)(bn + row) * K + k0 + csrc * 8;
            gload_lds16(srcB, Bs + (size_t)(ldsbase - (char*)0));
        }
        __syncthreads();
        int c16 = lane >> 4;
        bf16x8 af[4], bfr[4];
#pragma unroll
        for (int m = 0; m < 4; ++m)
            af[m] = *(const bf16x8*)(As + swz((wr << 6) + (m << 4) + (lane & 15), c16));
#pragma unroll
        for (int n = 0; n < 4; ++n)
            bfr[n] = *(const bf16x8*)(Bs + swz((wc << 6) + (n << 4) + (lane & 15), c16));
#pragma unroll
        for (int m = 0; m < 4; ++m)
#pragma unroll
            for (int n = 0; n < 4; ++n)
                acc[m][n] = __builtin_amdgcn_mfma_f32_16x16x32_bf16(af[m], bfr[n], acc[m][n], 0, 0, 0);
        __syncthreads();
    }
#pragma unroll
    for (int m = 0; m < 4; ++m) {
#pragma unroll
        for (int n = 0; n < 4; ++n) {
            int row0 = bm + (wr << 6) + (m << 4) + ((lane >> 4) << 2);
            int col = bn + (wc << 6) + (n << 4) + (lane & 15);
            float bv = bias ? bias[col] : 0.f;
#pragma unroll
            for (int j = 0; j < 4; ++j) {
                float v = acc[m][n][j] + bv;
                if (ACT == 1) v = fmaxf(v, 0.f);
                if (OBF) {
                    unsigned short* C = (unsigned short*)Cg + (size_t)blockIdx.z * czs;
                    C[(size_t)(row0 + j) * ldc + col] = f2bf(v);
                } else {
                    float* C = (float*)Cg + (size_t)blockIdx.z * czs;
                    C[(size_t)(row0 + j) * ldc + col] = v;
                }
            }
        }
    }
}

// ================= f32 fallback GEMM (small K / small N) =================
template <int ACT>
__global__ __launch_bounds__(256) void gemm_k(
    const float* __restrict__ A, int K,
    const float* __restrict__ Wg, int Jw,
    const float* __restrict__ bias,
    float* __restrict__ Cg, int ldc, int jmax,
    size_t wzs, size_t czs)
{
    __shared__ float Ash[16][64];
    __shared__ float Bsh[16][68];
    const float* W = Wg + (size_t)blockIdx.z * wzs;
    float* C = Cg + (size_t)blockIdx.z * czs;
    int tid = threadIdx.x;
    int bj = blockIdx.x << 6;
    int bm = blockIdx.y << 6;
    int tx = tid & 15, ty = tid >> 4;
    float acc[4][4] = {};
    int ktn = (K + 15) >> 4;
    int ar = tid >> 2;
    int aks = (tid & 3) << 2;
    int wk = tid >> 4;
    int wjs = (tid & 15) << 2;
    for (int kt = 0; kt < ktn; ++kt) {
        int k0 = kt << 4;
        const float* Ap = A + (size_t)(bm + ar) * K + k0 + aks;
#pragma unroll
        for (int i = 0; i < 4; ++i) {
            int k = k0 + aks + i;
            Ash[aks + i][ar] = (k < K) ? Ap[i] : 0.f;
        }
        const float* Wp = W + (size_t)(k0 + wk) * Jw + bj + wjs;
        bool kok = (k0 + wk) < K;
#pragma unroll
        for (int i = 0; i < 4; ++i) {
            int j = bj + wjs + i;
            Bsh[wk][wjs + i] = (kok && j < jmax) ? Wp[i] : 0.f;
        }
        __syncthreads();
#pragma unroll
        for (int kk = 0; kk < 16; ++kk) {
            const float4 av = *reinterpret_cast<const float4*>(&Ash[kk][ty << 2]);
            const float4 bv = *reinterpret_cast<const float4*>(&Bsh[kk][tx << 2]);
            float aa[4] = {av.x, av.y, av.z, av.w};
            float bb[4] = {bv.x, bv.y, bv.z, bv.w};
#pragma unroll
            for (int i = 0; i < 4; ++i)
#pragma unroll
                for (int j = 0; j < 4; ++j)
                    acc[i][j] = fmaf(aa[i], bb[j], acc[i][j]);
        }
        __syncthreads();
    }
#pragma unroll
    for (int i = 0; i < 4; ++i) {
        int row = bm + (ty << 2) + i;
#pragma unroll
        for (int j = 0; j < 4; ++j) {
            int col = bj + (tx << 2) + j;
            if (col < jmax) {
                float v = acc[i][j];
                if (bias) v += bias[col];
                if (ACT == 1) v = fmaxf(v, 0.f);
                C[(size_t)row * ldc + col] = v;
            }
        }
    }
}

// ================= weight transpose + bf16 convert =================
__global__ void transpose_bf(const float* __restrict__ W, unsigned short* __restrict__ Wt,
                             int K, int N, int total) {
    int i = blockIdx.x * 256 + threadIdx.x;
    if (i >= total) return;
    int kn = K * N;
    int z = i / kn, rem = i - z * kn;
    int k = rem / N, n = rem - k * N;
    Wt[(size_t)z * kn + (size_t)n * K + k] = f2bf(W[i]);
}

// ================= CSR build =================
__global__ void csr_count(const int* __restrict__ eo, const int* __restrict__ ea,
                          const int* __restrict__ es, int* __restrict__ deg) {
    int e = blockIdx.x * 256 + threadIdx.x;
    if (e >= ETOT) return;
    int et = e >> 16, le = e & 65535;
    const int* ei = et == 0 ? eo : (et == 1 ? ea : es);
    atomicAdd(&deg[ei[EE + le]], 1);
}
__global__ void csr_alloc(const int* __restrict__ deg, int* __restrict__ counter,
                          int* __restrict__ rps) {
    int n = blockIdx.x * 256 + threadIdx.x;
    if (n < NN) rps[n] = atomicAdd(counter, deg[n]);
}
__global__ void csr_fill(const int* __restrict__ eo, const int* __restrict__ ea,
                         const int* __restrict__ es, const int* __restrict__ rps,
                         int* __restrict__ fill, int* __restrict__ elist) {
    int e = blockIdx.x * 256 + threadIdx.x;
    if (e >= ETOT) return;
    int et = e >> 16, le = e & 65535;
    const int* ei = et == 0 ? eo : (et == 1 ? ea : es);
    int src = ei[le], dst = ei[EE + le];
    int pos = rps[dst] + atomicAdd(&fill[dst], 1);
    elist[pos] = (et << 16) | src;
}

// ================= misc =================
__global__ void count_nodes(const int* __restrict__ batch, float* __restrict__ gcnt) {
    int n = blockIdx.x * 256 + threadIdx.x;
    if (n < NN) atomicAdd(&gcnt[batch[n]], 1.f);
}

// single contiguous pass over h0, 3 accumulator pairs (branch-selected, no runtime idx)
__global__ __launch_bounds__(256) void enc_reduce_all(const float* __restrict__ h0, float* __restrict__ est) {
    float a1 = 0.f, a2 = 0.f, b1 = 0.f, b2 = 0.f, c1 = 0.f, c2 = 0.f;
    for (long i = blockIdx.x * 256 + threadIdx.x; i < (long)NN * FF; i += (long)gridDim.x * 256) {
        float v = h0[i];
        int enc = (int)(i % FF) >> 7;
        if (enc == 0)      { a1 += v; a2 += v * v; }
        else if (enc == 1) { b1 += v; b2 += v * v; }
        else               { c1 += v; c2 += v * v; }
    }
    a1 = wave_sum(a1); a2 = wave_sum(a2);
    b1 = wave_sum(b1); b2 = wave_sum(b2);
    c1 = wave_sum(c1); c2 = wave_sum(c2);
    if ((threadIdx.x & 63) == 0) {
        atomicAdd(&est[0], a1); atomicAdd(&est[1], a2);
        atomicAdd(&est[2], b1); atomicAdd(&est[3], b2);
        atomicAdd(&est[4], c1); atomicAdd(&est[5], c2);
    }
}

__global__ void enc_finalize(float* est) {
    int i = threadIdx.x;
    if (i < 3) {
        float cnt = (float)NN * 128.f;
        float mean = est[2 * i] / cnt;
        float var = est[2 * i + 1] / cnt - mean * mean;
        var = fmaxf(var, 0.f);
        est[6 + 2 * i] = mean;
        est[7 + 2 * i] = 1.f / (sqrtf(var) + 1e-5f);
    }
}

__global__ __launch_bounds__(256) void enc_apply(
    float* __restrict__ h0, unsigned short* __restrict__ hb, const float* __restrict__ est,
    const float* __restrict__ lw0, const float* __restrict__ lb0,
    const float* __restrict__ lw1, const float* __restrict__ lb1,
    const float* __restrict__ lw2, const float* __restrict__ lb2)
{
    long gt = (long)blockIdx.x * 256 + threadIdx.x;
    if (gt >= (long)NN * FF) return;
    int f = (int)(gt % FF);
    int enc = f >> 7, j = f & 127;
    const float* lw = enc == 0 ? lw0 : (enc == 1 ? lw1 : lw2);
    const float* lb = enc == 0 ? lb0 : (enc == 1 ? lb1 : lb2);
    float mean = est[6 + 2 * enc], sc = est[7 + 2 * enc];
    float v = (h0[gt] - mean) * sc * lw[j] + lb[j];
    h0[gt] = v;
    hb[gt] = f2bf(v);
}

// ================= qi/kj via MFMA: [3N,384] @ [384,16] =================
__global__ __launch_bounds__(256) void qk_mfma(
    const unsigned short* __restrict__ xt,
    const float* __restrict__ q, const float* __restrict__ k,
    float* __restrict__ qi, float* __restrict__ kj)
{
    __shared__ __align__(16) unsigned short qkT[16 * 392];
    int t = threadIdx.x;
    for (int idx = t; idx < 16 * 384; idx += 256) {
        int row = idx / 384, f = idx - row * 384;
        float v = (row < 8) ? q[f * 8 + row] : k[f * 8 + row - 8];
        qkT[row * 392 + f] = f2bf(v);
    }
    __syncthreads();
    int lane = t & 63, wid = t >> 6;
    int col = lane & 15, kq = lane >> 4;
    bf16x8 bfrag[12];
#pragma unroll
    for (int kt = 0; kt < 12; ++kt)
        bfrag[kt] = *(const bf16x8*)(qkT + col * 392 + kt * 32 + kq * 8);
    int tile = blockIdx.x * 4 + wid;
    const unsigned short* arow = xt + (size_t)(tile * 16 + col) * FF + kq * 8;
    f32x4 acc = {};
#pragma unroll
    for (int kt = 0; kt < 12; ++kt) {
        bf16x8 af = *(const bf16x8*)(arow + kt * 32);
        acc = __builtin_amdgcn_mfma_f32_16x16x32_bf16(af, bfrag[kt], acc, 0, 0, 0);
    }
    int row0 = kq << 2;
#pragma unroll
    for (int j = 0; j < 4; ++j) {
        size_t node = (size_t)tile * 16 + row0 + j;
        float v = acc[j];
        if (col < 8) qi[node * 8 + col] = v;
        else         kj[node * 8 + col - 8] = v;
    }
}

// ================= per-(node,head) online max/sum; stores raw alpha =================
__global__ __launch_bounds__(256) void msum_kernel(
    const int* __restrict__ rps, const int* __restrict__ deg, const int* __restrict__ elist,
    const float* __restrict__ qi, const float* __restrict__ kj,
    float* __restrict__ wav, float* __restrict__ sden, float* __restrict__ mbuf)
{
    int t = blockIdx.x * 256 + threadIdx.x;  // node*8 + h
    if (t >= NN * 8) return;
    int node = t >> 3, h = t & 7;
    int d = deg[node], rp = rps[node];
    float qv0 = qi[(size_t)node * 8 + h];
    float qv1 = qi[((size_t)NN + node) * 8 + h];
    float qv2 = qi[((size_t)2 * NN + node) * 8 + h];
    float m = -3.4e38f, s = 0.f;
    for (int b = 0; b < d; b += 4) {
        int p0 = (b + 0 < d) ? elist[rp + b + 0] : -1;
        int p1 = (b + 1 < d) ? elist[rp + b + 1] : -1;
        int p2 = (b + 2 < d) ? elist[rp + b + 2] : -1;
        int p3 = (b + 3 < d) ? elist[rp + b + 3] : -1;
        float a0 = -3.4e38f, a1 = -3.4e38f, a2 = -3.4e38f, a3 = -3.4e38f;
        if (p0 >= 0) { int et = p0 >> 16, sr = p0 & 0xFFFF; float qv = et == 0 ? qv0 : (et == 1 ? qv1 : qv2);
                       float a = qv + kj[((size_t)et * NN + sr) * 8 + h]; a0 = a >= 0.f ? a : NEG_SLOPE * a; }
        if (p1 >= 0) { int et = p1 >> 16, sr = p1 & 0xFFFF; float qv = et == 0 ? qv0 : (et == 1 ? qv1 : qv2);
                       float a = qv + kj[((size_t)et * NN + sr) * 8 + h]; a1 = a >= 0.f ? a : NEG_SLOPE * a; }
        if (p2 >= 0) { int et = p2 >> 16, sr = p2 & 0xFFFF; float qv = et == 0 ? qv0 : (et == 1 ? qv1 : qv2);
                       float a = qv + kj[((size_t)et * NN + sr) * 8 + h]; a2 = a >= 0.f ? a : NEG_SLOPE * a; }
        if (p3 >= 0) { int et = p3 >> 16, sr = p3 & 0xFFFF; float qv = et == 0 ? qv0 : (et == 1 ? qv1 : qv2);
                       float a = qv + kj[((size_t)et * NN + sr) * 8 + h]; a3 = a >= 0.f ? a : NEG_SLOPE * a; }
        float mb = fmaxf(fmaxf(a0, a1), fmaxf(a2, a3));
        float mn = fmaxf(m, mb);
        s *= __expf(m - mn);  // first iter: exp(-inf)=0, s stays 0
        if (p0 >= 0) { wav[(size_t)(rp + b + 0) * 8 + h] = a0; s += __expf(a0 - mn); }
        if (p1 >= 0) { wav[(size_t)(rp + b + 1) * 8 + h] = a1; s += __expf(a1 - mn); }
        if (p2 >= 0) { wav[(size_t)(rp + b + 2) * 8 + h] = a2; s += __expf(a2 - mn); }
        if (p3 >= 0) { wav[(size_t)(rp + b + 3) * 8 + h] = a3; s += __expf(a3 - mn); }
        m = mn;
    }
    sden[t] = 1.f / (s + 1e-16f);
    mbuf[t] = m;
}

// ================= weighted gather + elu + residual + graph stats (4-deep MLP) =================
__global__ __launch_bounds__(256) void gather_fused(
    const int* __restrict__ rps, const int* __restrict__ deg, const int* __restrict__ elist,
    const float* __restrict__ wav, const float* __restrict__ sden, const float* __restrict__ mbuf,
    const unsigned short* __restrict__ xt,
    const float* __restrict__ hin, const float* __restrict__ rb, const int* __restrict__ batch,
    float* __restrict__ gs1, float* __restrict__ gs2, float* __restrict__ ybuf)
{
    int node = blockIdx.x * 4 + (threadIdx.x >> 6);
    int lane = threadIdx.x & 63;
    int d = deg[node], rp = rps[node];
    int head = lane >> 3;
    float inv = sden[node * 8 + head];
    float mh = mbuf[node * 8 + head];
    int f0 = lane * 6;
    float acc0 = 0.f, acc1 = 0.f, acc2 = 0.f, acc3 = 0.f, acc4 = 0.f, acc5 = 0.f;
    for (int b = 0; b < d; b += 4) {
        int p0 = (b + 0 < d) ? elist[rp + b + 0] : -1;
        int p1 = (b + 1 < d) ? elist[rp + b + 1] : -1;
        int p2 = (b + 2 < d) ? elist[rp + b + 2] : -1;
        int p3 = (b + 3 < d) ? elist[rp + b + 3] : -1;
        float w0 = (p0 >= 0) ? __expf(wav[(size_t)(rp + b + 0) * 8 + head] - mh) * inv : 0.f;
        float w1 = (p1 >= 0) ? __expf(wav[(size_t)(rp + b + 1) * 8 + head] - mh) * inv : 0.f;
        float w2 = (p2 >= 0) ? __expf(wav[(size_t)(rp + b + 2) * 8 + head] - mh) * inv : 0.f;
        float w3 = (p3 >= 0) ? __expf(wav[(size_t)(rp + b + 3) * 8 + head] - mh) * inv : 0.f;
        unsigned u00 = 0, u01 = 0, u02 = 0, u10 = 0, u11 = 0, u12 = 0;
        unsigned u20 = 0, u21 = 0, u22 = 0, u30 = 0, u31 = 0, u32 = 0;
        if (p0 >= 0) { const unsigned* xr = (const unsigned*)(xt + ((size_t)(p0 >> 16) * NN + (p0 & 0xFFFF)) * FF) + lane * 3;
                       u00 = xr[0]; u01 = xr[1]; u02 = xr[2]; }
        if (p1 >= 0) { const unsigned* xr = (const unsigned*)(xt + ((size_t)(p1 >> 16) * NN + (p1 & 0xFFFF)) * FF) + lane * 3;
                       u10 = xr[0]; u11 = xr[1]; u12 = xr[2]; }
        if (p2 >= 0) { const unsigned* xr = (const unsigned*)(xt + ((size_t)(p2 >> 16) * NN + (p2 & 0xFFFF)) * FF) + lane * 3;
                       u20 = xr[0]; u21 = xr[1]; u22 = xr[2]; }
        if (p3 >= 0) { const unsigned* xr = (const unsigned*)(xt + ((size_t)(p3 >> 16) * NN + (p3 & 0xFFFF)) * FF) + lane * 3;
                       u30 = xr[0]; u31 = xr[1]; u32 = xr[2]; }
        acc0 = fmaf(w0, bflo(u00), acc0); acc1 = fmaf(w0, bfhi(u00), acc1);
        acc2 = fmaf(w0, bflo(u01), acc2); acc3 = fmaf(w0, bfhi(u01), acc3);
        acc4 = fmaf(w0, bflo(u02), acc4); acc5 = fmaf(w0, bfhi(u02), acc5);
        acc0 = fmaf(w1, bflo(u10), acc0); acc1 = fmaf(w1, bfhi(u10), acc1);
        acc2 = fmaf(w1, bflo(u11), acc2); acc3 = fmaf(w1, bfhi(u11), acc3);
        acc4 = fmaf(w1, bflo(u12), acc4); acc5 = fmaf(w1, bfhi(u12), acc5);
        acc0 = fmaf(w2, bflo(u20), acc0); acc1 = fmaf(w2, bfhi(u20), acc1);
        acc2 = fmaf(w2, bflo(u21), acc2); acc3 = fmaf(w2, bfhi(u21), acc3);
        acc4 = fmaf(w2, bflo(u22), acc4); acc5 = fmaf(w2, bfhi(u22), acc5);
        acc0 = fmaf(w3, bflo(u30), acc0); acc1 = fmaf(w3, bfhi(u30), acc1);
        acc2 = fmaf(w3, bflo(u31), acc2); acc3 = fmaf(w3, bfhi(u31), acc3);
        acc4 = fmaf(w3, bflo(u32), acc4); acc5 = fmaf(w3, bfhi(u32), acc5);
    }
    float s1 = 0.f, s2 = 0.f;
    float av[6] = {acc0, acc1, acc2, acc3, acc4, acc5};
#pragma unroll
    for (int i = 0; i < 6; ++i) {
        int f = f0 + i;
        float mv = av[i] + rb[f];
        float e = mv > 0.f ? mv : (__expf(mv) - 1.f);
        float y = hin[(size_t)node * FF + f] + e;
        ybuf[(size_t)node * FF + f] = y;
        s1 += y; s2 += y * y;
    }
    s1 = wave_sum(s1);
    s2 = wave_sum(s2);
    if (lane == 0) {
        int g = batch[node];
        atomicAdd(&gs1[g], s1);
        atomicAdd(&gs2[g], s2);
    }
}

__global__ void graph_finalize(
    const float* __restrict__ gcnt, const float* __restrict__ gs1, const float* __restrict__ gs2,
    float* __restrict__ gmean, float* __restrict__ grstd)
{
    int g = blockIdx.x * 64 + threadIdx.x;
    if (g >= GG) return;
    float cnt = fmaxf(gcnt[g], 1.f) * (float)FF;
    float mean = gs1[g] / cnt;
    float var = gs2[g] / cnt - mean * mean;
    var = fmaxf(var, 0.f);
    gmean[g] = mean;
    grstd[g] = 1.f / sqrtf(var + 1e-5f);
}

__global__ __launch_bounds__(256) void ln_apply(
    const float* __restrict__ y, const int* __restrict__ batch,
    const float* __restrict__ gmean, const float* __restrict__ grstd,
    const float* __restrict__ w, const float* __restrict__ b,
    float* __restrict__ hout, unsigned short* __restrict__ hb)
{
    long gt = (long)blockIdx.x * 256 + threadIdx.x;
    int n = (int)(gt >> 6);
    if (n >= NN) return;
    int lane = (int)(gt & 63);
    int f0 = lane * 6;
    int g = batch[n];
    float mean = gmean[g], rs = grstd[g];
#pragma unroll
    for (int i = 0; i < 6; ++i) {
        int f = f0 + i;
        float v = (y[(size_t)n * FF + f] - mean) * rs * w[f] + b[f];
        hout[(size_t)n * FF + f] = v;
        hb[(size_t)n * FF + f] = f2bf(v);
    }
}

// ================= host-side layer driver =================
static void rgat_layer(hipStream_t stream,
    const float* hin, const unsigned short* hbA,
    const float* rw, const float* rq, const float* rk, const float* rb,
    const float* lnw, const float* lnb,
    const int* rps, const int* deg, const int* elist, const int* batch,
    unsigned short* wt, unsigned short* xt, float* qi, float* kj,
    float* wav, float* sden, float* mbuf,
    float* gs1, float* gs2, const float* gcnt, float* gmean, float* grstd,
    float* ybuf, float* hout, unsigned short* hbOut)
{
    hipMemsetAsync(gs1, 0, GG * 4, stream);
    hipMemsetAsync(gs2, 0, GG * 4, stream);
    int tt = 3 * FF * FF;
    transpose_bf<<<(tt + 255) / 256, 256, 0, stream>>>(rw, wt, FF, FF, tt);
    gemm_mfma<0, true, true><<<dim3(3, 384, 3), 256, 0, stream>>>(
        hbA, FF, wt, nullptr, xt, FF, (size_t)FF * FF, (size_t)NN * FF);
    qk_mfma<<<3 * NN / 64, 256, 0, stream>>>(xt, rq, rk, qi, kj);
    msum_kernel<<<NN * 8 / 256, 256, 0, stream>>>(rps, deg, elist, qi, kj, wav, sden, mbuf);
    gather_fused<<<NN / 4, 256, 0, stream>>>(rps, deg, elist, wav, sden, mbuf, xt, hin, rb, batch, gs1, gs2, ybuf);
    graph_finalize<<<GG / 64, 64, 0, stream>>>(gcnt, gs1, gs2, gmean, grstd);
    ln_apply<<<NN / 4, 256, 0, stream>>>(ybuf, batch, gmean, grstd, lnw, lnb, hout, hbOut);
}

extern "C" void kernel_launch(void* const* d_in, const int* in_sizes, int n_in,
                              void* d_out, int out_size, void* d_ws, size_t ws_size,
                              hipStream_t stream)
{
    const float* x_visual = (const float*)d_in[0];
    const float* x_geom   = (const float*)d_in[1];
    const float* x_prior  = (const float*)d_in[2];
    const float* vis_w  = (const float*)d_in[3];
    const float* vis_b  = (const float*)d_in[4];
    const float* vis_lw = (const float*)d_in[5];
    const float* vis_lb = (const float*)d_in[6];
    const float* geom_w  = (const float*)d_in[7];
    const float* geom_b  = (const float*)d_in[8];
    const float* geom_lw = (const float*)d_in[9];
    const float* geom_lb = (const float*)d_in[10];
    const float* prior_w  = (const float*)d_in[11];
    const float* prior_b  = (const float*)d_in[12];
    const float* prior_lw = (const float*)d_in[13];
    const float* prior_lb = (const float*)d_in[14];
    const float* r1_w = (const float*)d_in[15];
    const float* r1_q = (const float*)d_in[16];
    const float* r1_k = (const float*)d_in[17];
    const float* r1_b = (const float*)d_in[18];
    const float* n1_w = (const float*)d_in[19];
    const float* n1_b = (const float*)d_in[20];
    const float* r2_w = (const float*)d_in[21];
    const float* r2_q = (const float*)d_in[22];
    const float* r2_k = (const float*)d_in[23];
    const float* r2_b = (const float*)d_in[24];
    const float* n2_w = (const float*)d_in[25];
    const float* n2_b = (const float*)d_in[26];
    const float* c_w1 = (const float*)d_in[27];
    const float* c_b1 = (const float*)d_in[28];
    const float* c_w2 = (const float*)d_in[29];
    const float* c_b2 = (const float*)d_in[30];
    const int* ei_o  = (const int*)d_in[31];
    const int* ei_a  = (const int*)d_in[32];
    const int* ei_s  = (const int*)d_in[33];
    const int* batch = (const int*)d_in[34];
    float* out = (float*)d_out;

    char* p = (char*)d_ws;
    auto alloc = [&](size_t bytes) { char* r = p; p += (bytes + 255) & ~(size_t)255; return r; };
    float* h0 = (float*)alloc((size_t)NN * FF * 4);
    float* h1 = (float*)alloc((size_t)NN * FF * 4);
    float* ybuf = (float*)alloc((size_t)NN * FF * 4);
    unsigned short* xt = (unsigned short*)alloc((size_t)3 * NN * FF * 2);
    unsigned short* hb = (unsigned short*)alloc((size_t)NN * FF * 2);
    unsigned short* wt = (unsigned short*)alloc((size_t)3 * FF * FF * 2);
    float* t128 = (float*)alloc((size_t)NN * 128 * 4);
    float* qi = (float*)alloc((size_t)3 * NN * 8 * 4);
    float* kj = (float*)alloc((size_t)3 * NN * 8 * 4);
    float* wav = (float*)alloc((size_t)ETOT * 8 * 4);
    float* sden = (float*)alloc((size_t)NN * 8 * 4);
    float* mbuf = (float*)alloc((size_t)NN * 8 * 4);
    int* deg = (int*)alloc(NN * 4);
    int* rps = (int*)alloc(NN * 4);
    int* fill = (int*)alloc(NN * 4);
    int* elist = (int*)alloc(ETOT * 4);
    int* counter = (int*)alloc(256);
    float* gs1 = (float*)alloc(GG * 4);
    float* gs2 = (float*)alloc(GG * 4);
    float* gcnt = (float*)alloc(GG * 4);
    float* gmean = (float*)alloc(GG * 4);
    float* grstd = (float*)alloc(GG * 4);
    float* est = (float*)alloc(64);
    float* h2 = h0;  // reuse

    // ---- CSR build (once; shared by both layers) ----
    hipMemsetAsync(deg, 0, NN * 4, stream);
    hipMemsetAsync(fill, 0, NN * 4, stream);
    hipMemsetAsync(counter, 0, 4, stream);
    csr_count<<<ETOT / 256, 256, 0, stream>>>(ei_o, ei_a, ei_s, deg);
    csr_alloc<<<NN / 256, 256, 0, stream>>>(deg, counter, rps);
    csr_fill<<<ETOT / 256, 256, 0, stream>>>(ei_o, ei_a, ei_s, rps, fill, elist);

    // ---- per-graph node counts ----
    hipMemsetAsync(gcnt, 0, GG * 4, stream);
    count_nodes<<<NN / 256, 256, 0, stream>>>(batch, gcnt);

    // ---- encoders ----
    hipMemsetAsync(est, 0, 64, stream);
    transpose_bf<<<(1024 * 128 + 255) / 256, 256, 0, stream>>>(vis_w, wt, 1024, 128, 1024 * 128);
    gemm_mfma<1, false, false><<<dim3(1, 384, 1), 256, 0, stream>>>(
        x_visual, 1024, wt, vis_b, h0, FF, 0, 0);
    gemm_k<1><<<dim3(2, 768, 1), 256, 0, stream>>>(x_geom, 6, geom_w, 128, geom_b, h0 + 128, FF, 128, 0, 0);
    gemm_k<1><<<dim3(2, 768, 1), 256, 0, stream>>>(x_prior, 50, prior_w, 128, prior_b, h0 + 256, FF, 128, 0, 0);
    enc_reduce_all<<<1024, 256, 0, stream>>>(h0, est);
    enc_finalize<<<1, 64, 0, stream>>>(est);
    enc_apply<<<(int)((size_t)NN * FF / 256), 256, 0, stream>>>(
        h0, hb, est, vis_lw, vis_lb, geom_lw, geom_lb, prior_lw, prior_lb);

    // ---- RGAT layers ----
    rgat_layer(stream, h0, hb, r1_w, r1_q, r1_k, r1_b, n1_w, n1_b,
               rps, deg, elist, batch, wt, xt, qi, kj, wav, sden, mbuf,
               gs1, gs2, gcnt, gmean, grstd, ybuf, h1, hb);
    rgat_layer(stream, h1, hb, r2_w, r2_q, r2_k, r2_b, n2_w, n2_b,
               rps, deg, elist, batch, wt, xt, qi, kj, wav, sden, mbuf,
               gs1, gs2, gcnt, gmean, grstd, ybuf, h2, hb);

    // ---- classifier ----
    transpose_bf<<<(FF * 128 + 255) / 256, 256, 0, stream>>>(c_w1, wt, FF, 128, FF * 128);
    gemm_mfma<1, true, false><<<dim3(1, 384, 1), 256, 0, stream>>>(
        hb, FF, wt, c_b1, t128, 128, 0, 0);
    gemm_k<0><<<dim3(1, 768, 1), 256, 0, stream>>>(t128, 128, c_w2, 49, c_b2, out, 49, 49, 0, 0);
}

// Round 5
// 930.279 us; speedup vs baseline: 1.3420x; 1.3420x over previous
//
#include <hip/hip_runtime.h>
#include <hip/hip_bf16.h>

#define NN 49152
#define GG 1024
#define EE 65536
#define ETOT 196608
#define FF 384
#define NEG_SLOPE 0.2f

typedef __attribute__((ext_vector_type(8))) short bf16x8;
typedef __attribute__((ext_vector_type(4))) float f32x4;

__device__ __forceinline__ float wave_sum(float v) {
#pragma unroll
    for (int m = 32; m; m >>= 1) v += __shfl_xor(v, m);
    return v;
}
__device__ __forceinline__ unsigned short f2bf(float f) {
    __hip_bfloat16 b = __float2bfloat16(f);
    return *reinterpret_cast<unsigned short*>(&b);
}
__device__ __forceinline__ float bflo(unsigned u) { return __uint_as_float(u << 16); }
__device__ __forceinline__ float bfhi(unsigned u) { return __uint_as_float(u & 0xffff0000u); }

__device__ __forceinline__ void gload_lds16(const void* g, void* l) {
    __builtin_amdgcn_global_load_lds(
        (const __attribute__((address_space(1))) unsigned int*)g,
        (__attribute__((address_space(3))) unsigned int*)l, 16, 0, 0);
}

// ================= MFMA bf16 GEMM: C = act(A @ Bt^T + bias) =================
// Physical LDS convention: position (row, c) holds logical chunk c ^ ((row>>1)&3).
__device__ __forceinline__ int swz(int row, int c16) {
    return row * 64 + ((c16 ^ ((row >> 1) & 3)) << 4);
}

template <int ACT, bool ABF, bool OBF>
__global__ __launch_bounds__(256) void gemm_mfma(
    const void* __restrict__ Ag, int K,
    const unsigned short* __restrict__ Btg,
    const float* __restrict__ bias,
    void* __restrict__ Cg, int ldc,
    size_t bzs, size_t czs)
{
    __shared__ __align__(16) char As[8192];
    __shared__ __align__(16) char Bs[8192];
    const unsigned short* Bt = Btg + (size_t)blockIdx.z * bzs;
    int t = threadIdx.x;
    int bm = blockIdx.y << 7, bn = blockIdx.x << 7;
    int lane = t & 63, wid = t >> 6, wr = wid >> 1, wc = wid & 1;
    f32x4 acc[4][4] = {};
    int ktn = K >> 5;
    for (int kt = 0; kt < ktn; ++kt) {
        int k0 = kt << 5;
#pragma unroll
        for (int ii = 0; ii < 2; ++ii) {
            int id = t + (ii << 8);
            int row = id >> 2, c = id & 3;
            int csrc = c ^ ((row >> 1) & 3);  // pre-swizzled source chunk
            size_t ldsoff = (size_t)((wid << 10) + (ii << 12));  // wave-uniform offset
            if (ABF) {
                const unsigned short* srcA = (const unsigned short*)Ag + (size_t)(bm + row) * K + k0 + csrc * 8;
                gload_lds16(srcA, As + ldsoff);
            } else {
                const float* srcA = (const float*)Ag + (size_t)(bm + row) * K + k0 + c * 8;
                float4 a0 = *(const float4*)srcA;
                float4 a1 = *(const float4*)(srcA + 4);
                union { unsigned short u[8]; int4 v; } P;
                P.u[0] = f2bf(a0.x); P.u[1] = f2bf(a0.y); P.u[2] = f2bf(a0.z); P.u[3] = f2bf(a0.w);
                P.u[4] = f2bf(a1.x); P.u[5] = f2bf(a1.y); P.u[6] = f2bf(a1.z); P.u[7] = f2bf(a1.w);
                *(int4*)(As + swz(row, c)) = P.v;
            }
            const unsigned short* srcB = Bt + (size_t)(bn + row) * K + k0 + csrc * 8;
            gload_lds16(srcB, Bs + ldsoff);
        }
        __syncthreads();
        int c16 = lane >> 4;
        bf16x8 af[4], bfr[4];
#pragma unroll
        for (int m = 0; m < 4; ++m)
            af[m] = *(const bf16x8*)(As + swz((wr << 6) + (m << 4) + (lane & 15), c16));
#pragma unroll
        for (int n = 0; n < 4; ++n)
            bfr[n] = *(const bf16x8*)(Bs + swz((wc << 6) + (n << 4) + (lane & 15), c16));
#pragma unroll
        for (int m = 0; m < 4; ++m)
#pragma unroll
            for (int n = 0; n < 4; ++n)
                acc[m][n] = __builtin_amdgcn_mfma_f32_16x16x32_bf16(af[m], bfr[n], acc[m][n], 0, 0, 0);
        __syncthreads();
    }
#pragma unroll
    for (int m = 0; m < 4; ++m) {
#pragma unroll
        for (int n = 0; n < 4; ++n) {
            int row0 = bm + (wr << 6) + (m << 4) + ((lane >> 4) << 2);
            int col = bn + (wc << 6) + (n << 4) + (lane & 15);
            float bv = bias ? bias[col] : 0.f;
#pragma unroll
            for (int j = 0; j < 4; ++j) {
                float v = acc[m][n][j] + bv;
                if (ACT == 1) v = fmaxf(v, 0.f);
                if (OBF) {
                    unsigned short* C = (unsigned short*)Cg + (size_t)blockIdx.z * czs;
                    C[(size_t)(row0 + j) * ldc + col] = f2bf(v);
                } else {
                    float* C = (float*)Cg + (size_t)blockIdx.z * czs;
                    C[(size_t)(row0 + j) * ldc + col] = v;
                }
            }
        }
    }
}

// ================= f32 fallback GEMM (small K / small N) =================
template <int ACT>
__global__ __launch_bounds__(256) void gemm_k(
    const float* __restrict__ A, int K,
    const float* __restrict__ Wg, int Jw,
    const float* __restrict__ bias,
    float* __restrict__ Cg, int ldc, int jmax,
    size_t wzs, size_t czs)
{
    __shared__ float Ash[16][64];
    __shared__ float Bsh[16][68];
    const float* W = Wg + (size_t)blockIdx.z * wzs;
    float* C = Cg + (size_t)blockIdx.z * czs;
    int tid = threadIdx.x;
    int bj = blockIdx.x << 6;
    int bm = blockIdx.y << 6;
    int tx = tid & 15, ty = tid >> 4;
    float acc[4][4] = {};
    int ktn = (K + 15) >> 4;
    int ar = tid >> 2;
    int aks = (tid & 3) << 2;
    int wk = tid >> 4;
    int wjs = (tid & 15) << 2;
    for (int kt = 0; kt < ktn; ++kt) {
        int k0 = kt << 4;
        const float* Ap = A + (size_t)(bm + ar) * K + k0 + aks;
#pragma unroll
        for (int i = 0; i < 4; ++i) {
            int k = k0 + aks + i;
            Ash[aks + i][ar] = (k < K) ? Ap[i] : 0.f;
        }
        const float* Wp = W + (size_t)(k0 + wk) * Jw + bj + wjs;
        bool kok = (k0 + wk) < K;
#pragma unroll
        for (int i = 0; i < 4; ++i) {
            int j = bj + wjs + i;
            Bsh[wk][wjs + i] = (kok && j < jmax) ? Wp[i] : 0.f;
        }
        __syncthreads();
#pragma unroll
        for (int kk = 0; kk < 16; ++kk) {
            const float4 av = *reinterpret_cast<const float4*>(&Ash[kk][ty << 2]);
            const float4 bv = *reinterpret_cast<const float4*>(&Bsh[kk][tx << 2]);
            float aa[4] = {av.x, av.y, av.z, av.w};
            float bb[4] = {bv.x, bv.y, bv.z, bv.w};
#pragma unroll
            for (int i = 0; i < 4; ++i)
#pragma unroll
                for (int j = 0; j < 4; ++j)
                    acc[i][j] = fmaf(aa[i], bb[j], acc[i][j]);
        }
        __syncthreads();
    }
#pragma unroll
    for (int i = 0; i < 4; ++i) {
        int row = bm + (ty << 2) + i;
#pragma unroll
        for (int j = 0; j < 4; ++j) {
            int col = bj + (tx << 2) + j;
            if (col < jmax) {
                float v = acc[i][j];
                if (bias) v += bias[col];
                if (ACT == 1) v = fmaxf(v, 0.f);
                C[(size_t)row * ldc + col] = v;
            }
        }
    }
}

// ================= weight transpose + bf16 convert =================
__global__ void transpose_bf(const float* __restrict__ W, unsigned short* __restrict__ Wt,
                             int K, int N, int total) {
    int i = blockIdx.x * 256 + threadIdx.x;
    if (i >= total) return;
    int kn = K * N;
    int z = i / kn, rem = i - z * kn;
    int k = rem / N, n = rem - k * N;
    Wt[(size_t)z * kn + (size_t)n * K + k] = f2bf(W[i]);
}

// ================= CSR build =================
__global__ void csr_count(const int* __restrict__ eo, const int* __restrict__ ea,
                          const int* __restrict__ es, int* __restrict__ deg) {
    int e = blockIdx.x * 256 + threadIdx.x;
    if (e >= ETOT) return;
    int et = e >> 16, le = e & 65535;
    const int* ei = et == 0 ? eo : (et == 1 ? ea : es);
    atomicAdd(&deg[ei[EE + le]], 1);
}
// wave-scan allocation: 1 atomic per wave instead of per thread
__global__ void csr_alloc(const int* __restrict__ deg, int* __restrict__ counter,
                          int* __restrict__ rps) {
    int n = blockIdx.x * 256 + threadIdx.x;
    int lane = threadIdx.x & 63;
    int d = (n < NN) ? deg[n] : 0;
    int x = d;
#pragma unroll
    for (int off = 1; off < 64; off <<= 1) {
        int y = __shfl_up(x, off);
        if (lane >= off) x += y;
    }
    int total = __shfl(x, 63);
    int base = 0;
    if (lane == 63) base = atomicAdd(counter, total);
    base = __shfl(base, 63);
    if (n < NN) rps[n] = base + x - d;
}
__global__ void csr_fill(const int* __restrict__ eo, const int* __restrict__ ea,
                         const int* __restrict__ es, const int* __restrict__ rps,
                         int* __restrict__ fill, int* __restrict__ elist) {
    int e = blockIdx.x * 256 + threadIdx.x;
    if (e >= ETOT) return;
    int et = e >> 16, le = e & 65535;
    const int* ei = et == 0 ? eo : (et == 1 ? ea : es);
    int src = ei[le], dst = ei[EE + le];
    int pos = rps[dst] + atomicAdd(&fill[dst], 1);
    elist[pos] = (et << 16) | src;
}

// ================= misc =================
__global__ void count_nodes(const int* __restrict__ batch, float* __restrict__ gcnt) {
    int n = blockIdx.x * 256 + threadIdx.x;
    if (n < NN) atomicAdd(&gcnt[batch[n]], 1.f);
}

// ================= encoder stats: two-stage, no atomics =================
#define ERB 512  // stage-1 blocks
__global__ __launch_bounds__(256) void enc_reduce_stage1(const float* __restrict__ h0, float* __restrict__ pbuf) {
    __shared__ float part[4][6];
    float a1 = 0.f, a2 = 0.f, b1 = 0.f, b2 = 0.f, c1 = 0.f, c2 = 0.f;
    const float4* h4 = (const float4*)h0;
    int total4 = NN * FF / 4;  // 4.7M
    for (int i = blockIdx.x * 256 + threadIdx.x; i < total4; i += ERB * 256) {
        float4 v = h4[i];
        float s1 = v.x + v.y + v.z + v.w;
        float s2 = v.x * v.x + v.y * v.y + v.z * v.z + v.w * v.w;
        int enc = (i % 96) >> 5;  // float4 idx within row: 0-31/32-63/64-95
        if (enc == 0)      { a1 += s1; a2 += s2; }
        else if (enc == 1) { b1 += s1; b2 += s2; }
        else               { c1 += s1; c2 += s2; }
    }
    a1 = wave_sum(a1); a2 = wave_sum(a2);
    b1 = wave_sum(b1); b2 = wave_sum(b2);
    c1 = wave_sum(c1); c2 = wave_sum(c2);
    int w = threadIdx.x >> 6;
    if ((threadIdx.x & 63) == 0) {
        part[w][0] = a1; part[w][1] = a2; part[w][2] = b1;
        part[w][3] = b2; part[w][4] = c1; part[w][5] = c2;
    }
    __syncthreads();
    if (threadIdx.x < 6) {
        float s = part[0][threadIdx.x] + part[1][threadIdx.x] + part[2][threadIdx.x] + part[3][threadIdx.x];
        pbuf[blockIdx.x * 6 + threadIdx.x] = s;
    }
}

__global__ void enc_reduce_stage2(const float* __restrict__ pbuf, float* __restrict__ est) {
    int lane = threadIdx.x;  // 64 threads
    float s[6] = {};
    for (int b = lane; b < ERB; b += 64)
#pragma unroll
        for (int j = 0; j < 6; ++j) s[j] += pbuf[b * 6 + j];
#pragma unroll
    for (int j = 0; j < 6; ++j) {
        float v = wave_sum(s[j]);
        if (lane == 0) est[j] = v;
    }
    __syncthreads();
    if (lane < 3) {
        float cnt = (float)NN * 128.f;
        float mean = est[2 * lane] / cnt;
        float var = est[2 * lane + 1] / cnt - mean * mean;
        var = fmaxf(var, 0.f);
        est[6 + 2 * lane] = mean;
        est[7 + 2 * lane] = 1.f / (sqrtf(var) + 1e-5f);
    }
}

__global__ __launch_bounds__(256) void enc_apply(
    float* __restrict__ h0, unsigned short* __restrict__ hb, const float* __restrict__ est,
    const float* __restrict__ lw0, const float* __restrict__ lb0,
    const float* __restrict__ lw1, const float* __restrict__ lb1,
    const float* __restrict__ lw2, const float* __restrict__ lb2)
{
    long gt = (long)blockIdx.x * 256 + threadIdx.x;
    if (gt >= (long)NN * FF) return;
    int f = (int)(gt % FF);
    int enc = f >> 7, j = f & 127;
    const float* lw = enc == 0 ? lw0 : (enc == 1 ? lw1 : lw2);
    const float* lb = enc == 0 ? lb0 : (enc == 1 ? lb1 : lb2);
    float mean = est[6 + 2 * enc], sc = est[7 + 2 * enc];
    float v = (h0[gt] - mean) * sc * lw[j] + lb[j];
    h0[gt] = v;
    hb[gt] = f2bf(v);
}

// ================= qi/kj via MFMA: [3N,384] @ [384,16] =================
__global__ __launch_bounds__(256) void qk_mfma(
    const unsigned short* __restrict__ xt,
    const float* __restrict__ q, const float* __restrict__ k,
    float* __restrict__ qi, float* __restrict__ kj)
{
    __shared__ __align__(16) unsigned short qkT[16 * 392];
    int t = threadIdx.x;
    for (int idx = t; idx < 16 * 384; idx += 256) {
        int row = idx / 384, f = idx - row * 384;
        float v = (row < 8) ? q[f * 8 + row] : k[f * 8 + row - 8];
        qkT[row * 392 + f] = f2bf(v);
    }
    __syncthreads();
    int lane = t & 63, wid = t >> 6;
    int col = lane & 15, kq = lane >> 4;
    bf16x8 bfrag[12];
#pragma unroll
    for (int kt = 0; kt < 12; ++kt)
        bfrag[kt] = *(const bf16x8*)(qkT + col * 392 + kt * 32 + kq * 8);
    int tile = blockIdx.x * 4 + wid;
    const unsigned short* arow = xt + (size_t)(tile * 16 + col) * FF + kq * 8;
    f32x4 acc = {};
#pragma unroll
    for (int kt = 0; kt < 12; ++kt) {
        bf16x8 af = *(const bf16x8*)(arow + kt * 32);
        acc = __builtin_amdgcn_mfma_f32_16x16x32_bf16(af, bfrag[kt], acc, 0, 0, 0);
    }
    int row0 = kq << 2;
#pragma unroll
    for (int j = 0; j < 4; ++j) {
        size_t node = (size_t)tile * 16 + row0 + j;
        float v = acc[j];
        if (col < 8) qi[node * 8 + col] = v;
        else         kj[node * 8 + col - 8] = v;
    }
}

// ================= per-(node,head) online max/sum; stores raw alpha =================
__global__ __launch_bounds__(256) void msum_kernel(
    const int* __restrict__ rps, const int* __restrict__ deg, const int* __restrict__ elist,
    const float* __restrict__ qi, const float* __restrict__ kj,
    float* __restrict__ wav, float* __restrict__ sden, float* __restrict__ mbuf)
{
    int t = blockIdx.x * 256 + threadIdx.x;  // node*8 + h
    if (t >= NN * 8) return;
    int node = t >> 3, h = t & 7;
    int d = deg[node], rp = rps[node];
    float qv0 = qi[(size_t)node * 8 + h];
    float qv1 = qi[((size_t)NN + node) * 8 + h];
    float qv2 = qi[((size_t)2 * NN + node) * 8 + h];
    float m = -3.4e38f, s = 0.f;
    for (int b = 0; b < d; b += 4) {
        int p0 = (b + 0 < d) ? elist[rp + b + 0] : -1;
        int p1 = (b + 1 < d) ? elist[rp + b + 1] : -1;
        int p2 = (b + 2 < d) ? elist[rp + b + 2] : -1;
        int p3 = (b + 3 < d) ? elist[rp + b + 3] : -1;
        float a0 = -3.4e38f, a1 = -3.4e38f, a2 = -3.4e38f, a3 = -3.4e38f;
        if (p0 >= 0) { int et = p0 >> 16, sr = p0 & 0xFFFF; float qv = et == 0 ? qv0 : (et == 1 ? qv1 : qv2);
                       float a = qv + kj[((size_t)et * NN + sr) * 8 + h]; a0 = a >= 0.f ? a : NEG_SLOPE * a; }
        if (p1 >= 0) { int et = p1 >> 16, sr = p1 & 0xFFFF; float qv = et == 0 ? qv0 : (et == 1 ? qv1 : qv2);
                       float a = qv + kj[((size_t)et * NN + sr) * 8 + h]; a1 = a >= 0.f ? a : NEG_SLOPE * a; }
        if (p2 >= 0) { int et = p2 >> 16, sr = p2 & 0xFFFF; float qv = et == 0 ? qv0 : (et == 1 ? qv1 : qv2);
                       float a = qv + kj[((size_t)et * NN + sr) * 8 + h]; a2 = a >= 0.f ? a : NEG_SLOPE * a; }
        if (p3 >= 0) { int et = p3 >> 16, sr = p3 & 0xFFFF; float qv = et == 0 ? qv0 : (et == 1 ? qv1 : qv2);
                       float a = qv + kj[((size_t)et * NN + sr) * 8 + h]; a3 = a >= 0.f ? a : NEG_SLOPE * a; }
        float mb = fmaxf(fmaxf(a0, a1), fmaxf(a2, a3));
        float mn = fmaxf(m, mb);
        s *= __expf(m - mn);
        if (p0 >= 0) { wav[(size_t)(rp + b + 0) * 8 + h] = a0; s += __expf(a0 - mn); }
        if (p1 >= 0) { wav[(size_t)(rp + b + 1) * 8 + h] = a1; s += __expf(a1 - mn); }
        if (p2 >= 0) { wav[(size_t)(rp + b + 2) * 8 + h] = a2; s += __expf(a2 - mn); }
        if (p3 >= 0) { wav[(size_t)(rp + b + 3) * 8 + h] = a3; s += __expf(a3 - mn); }
        m = mn;
    }
    sden[t] = 1.f / (s + 1e-16f);
    mbuf[t] = m;
}

// ================= weighted gather + elu + residual + graph stats (4-deep MLP) =================
__global__ __launch_bounds__(256) void gather_fused(
    const int* __restrict__ rps, const int* __restrict__ deg, const int* __restrict__ elist,
    const float* __restrict__ wav, const float* __restrict__ sden, const float* __restrict__ mbuf,
    const unsigned short* __restrict__ xt,
    const float* __restrict__ hin, const float* __restrict__ rb, const int* __restrict__ batch,
    float* __restrict__ gs1, float* __restrict__ gs2, float* __restrict__ ybuf)
{
    int node = blockIdx.x * 4 + (threadIdx.x >> 6);
    int lane = threadIdx.x & 63;
    int d = deg[node], rp = rps[node];
    int head = lane >> 3;
    float inv = sden[node * 8 + head];
    float mh = mbuf[node * 8 + head];
    int f0 = lane * 6;
    float acc0 = 0.f, acc1 = 0.f, acc2 = 0.f, acc3 = 0.f, acc4 = 0.f, acc5 = 0.f;
    for (int b = 0; b < d; b += 4) {
        int p0 = (b + 0 < d) ? elist[rp + b + 0] : -1;
        int p1 = (b + 1 < d) ? elist[rp + b + 1] : -1;
        int p2 = (b + 2 < d) ? elist[rp + b + 2] : -1;
        int p3 = (b + 3 < d) ? elist[rp + b + 3] : -1;
        float w0 = (p0 >= 0) ? __expf(wav[(size_t)(rp + b + 0) * 8 + head] - mh) * inv : 0.f;
        float w1 = (p1 >= 0) ? __expf(wav[(size_t)(rp + b + 1) * 8 + head] - mh) * inv : 0.f;
        float w2 = (p2 >= 0) ? __expf(wav[(size_t)(rp + b + 2) * 8 + head] - mh) * inv : 0.f;
        float w3 = (p3 >= 0) ? __expf(wav[(size_t)(rp + b + 3) * 8 + head] - mh) * inv : 0.f;
        unsigned u00 = 0, u01 = 0, u02 = 0, u10 = 0, u11 = 0, u12 = 0;
        unsigned u20 = 0, u21 = 0, u22 = 0, u30 = 0, u31 = 0, u32 = 0;
        if (p0 >= 0) { const unsigned* xr = (const unsigned*)(xt + ((size_t)(p0 >> 16) * NN + (p0 & 0xFFFF)) * FF) + lane * 3;
                       u00 = xr[0]; u01 = xr[1]; u02 = xr[2]; }
        if (p1 >= 0) { const unsigned* xr = (const unsigned*)(xt + ((size_t)(p1 >> 16) * NN + (p1 & 0xFFFF)) * FF) + lane * 3;
                       u10 = xr[0]; u11 = xr[1]; u12 = xr[2]; }
        if (p2 >= 0) { const unsigned* xr = (const unsigned*)(xt + ((size_t)(p2 >> 16) * NN + (p2 & 0xFFFF)) * FF) + lane * 3;
                       u20 = xr[0]; u21 = xr[1]; u22 = xr[2]; }
        if (p3 >= 0) { const unsigned* xr = (const unsigned*)(xt + ((size_t)(p3 >> 16) * NN + (p3 & 0xFFFF)) * FF) + lane * 3;
                       u30 = xr[0]; u31 = xr[1]; u32 = xr[2]; }
        acc0 = fmaf(w0, bflo(u00), acc0); acc1 = fmaf(w0, bfhi(u00), acc1);
        acc2 = fmaf(w0, bflo(u01), acc2); acc3 = fmaf(w0, bfhi(u01), acc3);
        acc4 = fmaf(w0, bflo(u02), acc4); acc5 = fmaf(w0, bfhi(u02), acc5);
        acc0 = fmaf(w1, bflo(u10), acc0); acc1 = fmaf(w1, bfhi(u10), acc1);
        acc2 = fmaf(w1, bflo(u11), acc2); acc3 = fmaf(w1, bfhi(u11), acc3);
        acc4 = fmaf(w1, bflo(u12), acc4); acc5 = fmaf(w1, bfhi(u12), acc5);
        acc0 = fmaf(w2, bflo(u20), acc0); acc1 = fmaf(w2, bfhi(u20), acc1);
        acc2 = fmaf(w2, bflo(u21), acc2); acc3 = fmaf(w2, bfhi(u21), acc3);
        acc4 = fmaf(w2, bflo(u22), acc4); acc5 = fmaf(w2, bfhi(u22), acc5);
        acc0 = fmaf(w3, bflo(u30), acc0); acc1 = fmaf(w3, bfhi(u30), acc1);
        acc2 = fmaf(w3, bflo(u31), acc2); acc3 = fmaf(w3, bfhi(u31), acc3);
        acc4 = fmaf(w3, bflo(u32), acc4); acc5 = fmaf(w3, bfhi(u32), acc5);
    }
    float s1 = 0.f, s2 = 0.f;
    float av[6] = {acc0, acc1, acc2, acc3, acc4, acc5};
#pragma unroll
    for (int i = 0; i < 6; ++i) {
        int f = f0 + i;
        float mv = av[i] + rb[f];
        float e = mv > 0.f ? mv : (__expf(mv) - 1.f);
        float y = hin[(size_t)node * FF + f] + e;
        ybuf[(size_t)node * FF + f] = y;
        s1 += y; s2 += y * y;
    }
    s1 = wave_sum(s1);
    s2 = wave_sum(s2);
    if (lane == 0) {
        int g = batch[node];
        atomicAdd(&gs1[g], s1);
        atomicAdd(&gs2[g], s2);
    }
}

__global__ void graph_finalize(
    const float* __restrict__ gcnt, const float* __restrict__ gs1, const float* __restrict__ gs2,
    float* __restrict__ gmean, float* __restrict__ grstd)
{
    int g = blockIdx.x * 64 + threadIdx.x;
    if (g >= GG) return;
    float cnt = fmaxf(gcnt[g], 1.f) * (float)FF;
    float mean = gs1[g] / cnt;
    float var = gs2[g] / cnt - mean * mean;
    var = fmaxf(var, 0.f);
    gmean[g] = mean;
    grstd[g] = 1.f / sqrtf(var + 1e-5f);
}

__global__ __launch_bounds__(256) void ln_apply(
    const float* __restrict__ y, const int* __restrict__ batch,
    const float* __restrict__ gmean, const float* __restrict__ grstd,
    const float* __restrict__ w, const float* __restrict__ b,
    float* __restrict__ hout, unsigned short* __restrict__ hb)
{
    long gt = (long)blockIdx.x * 256 + threadIdx.x;
    int n = (int)(gt >> 6);
    if (n >= NN) return;
    int lane = (int)(gt & 63);
    int f0 = lane * 6;
    int g = batch[n];
    float mean = gmean[g], rs = grstd[g];
#pragma unroll
    for (int i = 0; i < 6; ++i) {
        int f = f0 + i;
        float v = (y[(size_t)n * FF + f] - mean) * rs * w[f] + b[f];
        hout[(size_t)n * FF + f] = v;
        hb[(size_t)n * FF + f] = f2bf(v);
    }
}

// ================= host-side layer driver =================
static void rgat_layer(hipStream_t stream,
    const float* hin, const unsigned short* hbA,
    const float* rw, const float* rq, const float* rk, const float* rb,
    const float* lnw, const float* lnb,
    const int* rps, const int* deg, const int* elist, const int* batch,
    unsigned short* wt, unsigned short* xt, float* qi, float* kj,
    float* wav, float* sden, float* mbuf,
    float* gs1, float* gs2, const float* gcnt, float* gmean, float* grstd,
    float* ybuf, float* hout, unsigned short* hbOut)
{
    hipMemsetAsync(gs1, 0, GG * 4, stream);
    hipMemsetAsync(gs2, 0, GG * 4, stream);
    int tt = 3 * FF * FF;
    transpose_bf<<<(tt + 255) / 256, 256, 0, stream>>>(rw, wt, FF, FF, tt);
    gemm_mfma<0, true, true><<<dim3(3, 384, 3), 256, 0, stream>>>(
        hbA, FF, wt, nullptr, xt, FF, (size_t)FF * FF, (size_t)NN * FF);
    qk_mfma<<<3 * NN / 64, 256, 0, stream>>>(xt, rq, rk, qi, kj);
    msum_kernel<<<NN * 8 / 256, 256, 0, stream>>>(rps, deg, elist, qi, kj, wav, sden, mbuf);
    gather_fused<<<NN / 4, 256, 0, stream>>>(rps, deg, elist, wav, sden, mbuf, xt, hin, rb, batch, gs1, gs2, ybuf);
    graph_finalize<<<GG / 64, 64, 0, stream>>>(gcnt, gs1, gs2, gmean, grstd);
    ln_apply<<<NN / 4, 256, 0, stream>>>(ybuf, batch, gmean, grstd, lnw, lnb, hout, hbOut);
}

extern "C" void kernel_launch(void* const* d_in, const int* in_sizes, int n_in,
                              void* d_out, int out_size, void* d_ws, size_t ws_size,
                              hipStream_t stream)
{
    const float* x_visual = (const float*)d_in[0];
    const float* x_geom   = (const float*)d_in[1];
    const float* x_prior  = (const float*)d_in[2];
    const float* vis_w  = (const float*)d_in[3];
    const float* vis_b  = (const float*)d_in[4];
    const float* vis_lw = (const float*)d_in[5];
    const float* vis_lb = (const float*)d_in[6];
    const float* geom_w  = (const float*)d_in[7];
    const float* geom_b  = (const float*)d_in[8];
    const float* geom_lw = (const float*)d_in[9];
    const float* geom_lb = (const float*)d_in[10];
    const float* prior_w  = (const float*)d_in[11];
    const float* prior_b  = (const float*)d_in[12];
    const float* prior_lw = (const float*)d_in[13];
    const float* prior_lb = (const float*)d_in[14];
    const float* r1_w = (const float*)d_in[15];
    const float* r1_q = (const float*)d_in[16];
    const float* r1_k = (const float*)d_in[17];
    const float* r1_b = (const float*)d_in[18];
    const float* n1_w = (const float*)d_in[19];
    const float* n1_b = (const float*)d_in[20];
    const float* r2_w = (const float*)d_in[21];
    const float* r2_q = (const float*)d_in[22];
    const float* r2_k = (const float*)d_in[23];
    const float* r2_b = (const float*)d_in[24];
    const float* n2_w = (const float*)d_in[25];
    const float* n2_b = (const float*)d_in[26];
    const float* c_w1 = (const float*)d_in[27];
    const float* c_b1 = (const float*)d_in[28];
    const float* c_w2 = (const float*)d_in[29];
    const float* c_b2 = (const float*)d_in[30];
    const int* ei_o  = (const int*)d_in[31];
    const int* ei_a  = (const int*)d_in[32];
    const int* ei_s  = (const int*)d_in[33];
    const int* batch = (const int*)d_in[34];
    float* out = (float*)d_out;

    char* p = (char*)d_ws;
    auto alloc = [&](size_t bytes) { char* r = p; p += (bytes + 255) & ~(size_t)255; return r; };
    float* h0 = (float*)alloc((size_t)NN * FF * 4);
    float* h1 = (float*)alloc((size_t)NN * FF * 4);
    float* ybuf = (float*)alloc((size_t)NN * FF * 4);
    unsigned short* xt = (unsigned short*)alloc((size_t)3 * NN * FF * 2);
    unsigned short* hb = (unsigned short*)alloc((size_t)NN * FF * 2);
    unsigned short* wt = (unsigned short*)alloc((size_t)3 * FF * FF * 2);
    float* t128 = (float*)alloc((size_t)NN * 128 * 4);
    float* qi = (float*)alloc((size_t)3 * NN * 8 * 4);
    float* kj = (float*)alloc((size_t)3 * NN * 8 * 4);
    float* wav = (float*)alloc((size_t)ETOT * 8 * 4);
    float* sden = (float*)alloc((size_t)NN * 8 * 4);
    float* mbuf = (float*)alloc((size_t)NN * 8 * 4);
    int* deg = (int*)alloc(NN * 4);
    int* rps = (int*)alloc(NN * 4);
    int* fill = (int*)alloc(NN * 4);
    int* elist = (int*)alloc(ETOT * 4);
    int* counter = (int*)alloc(256);
    float* gs1 = (float*)alloc(GG * 4);
    float* gs2 = (float*)alloc(GG * 4);
    float* gcnt = (float*)alloc(GG * 4);
    float* gmean = (float*)alloc(GG * 4);
    float* grstd = (float*)alloc(GG * 4);
    float* est = (float*)alloc(64);
    float* pbuf = (float*)alloc(ERB * 6 * 4);
    float* h2 = h0;  // reuse

    // ---- CSR build (once; shared by both layers) ----
    hipMemsetAsync(deg, 0, NN * 4, stream);
    hipMemsetAsync(fill, 0, NN * 4, stream);
    hipMemsetAsync(counter, 0, 4, stream);
    csr_count<<<ETOT / 256, 256, 0, stream>>>(ei_o, ei_a, ei_s, deg);
    csr_alloc<<<NN / 256, 256, 0, stream>>>(deg, counter, rps);
    csr_fill<<<ETOT / 256, 256, 0, stream>>>(ei_o, ei_a, ei_s, rps, fill, elist);

    // ---- per-graph node counts ----
    hipMemsetAsync(gcnt, 0, GG * 4, stream);
    count_nodes<<<NN / 256, 256, 0, stream>>>(batch, gcnt);

    // ---- encoders ----
    transpose_bf<<<(1024 * 128 + 255) / 256, 256, 0, stream>>>(vis_w, wt, 1024, 128, 1024 * 128);
    gemm_mfma<1, false, false><<<dim3(1, 384, 1), 256, 0, stream>>>(
        x_visual, 1024, wt, vis_b, h0, FF, 0, 0);
    gemm_k<1><<<dim3(2, 768, 1), 256, 0, stream>>>(x_geom, 6, geom_w, 128, geom_b, h0 + 128, FF, 128, 0, 0);
    gemm_k<1><<<dim3(2, 768, 1), 256, 0, stream>>>(x_prior, 50, prior_w, 128, prior_b, h0 + 256, FF, 128, 0, 0);
    enc_reduce_stage1<<<ERB, 256, 0, stream>>>(h0, pbuf);
    enc_reduce_stage2<<<1, 64, 0, stream>>>(pbuf, est);
    enc_apply<<<(int)((size_t)NN * FF / 256), 256, 0, stream>>>(
        h0, hb, est, vis_lw, vis_lb, geom_lw, geom_lb, prior_lw, prior_lb);

    // ---- RGAT layers ----
    rgat_layer(stream, h0, hb, r1_w, r1_q, r1_k, r1_b, n1_w, n1_b,
               rps, deg, elist, batch, wt, xt, qi, kj, wav, sden, mbuf,
               gs1, gs2, gcnt, gmean, grstd, ybuf, h1, hb);
    rgat_layer(stream, h1, hb, r2_w, r2_q, r2_k, r2_b, n2_w, n2_b,
               rps, deg, elist, batch, wt, xt, qi, kj, wav, sden, mbuf,
               gs1, gs2, gcnt, gmean, grstd, ybuf, h2, hb);

    // ---- classifier ----
    transpose_bf<<<(FF * 128 + 255) / 256, 256, 0, stream>>>(c_w1, wt, FF, 128, FF * 128);
    gemm_mfma<1, true, false><<<dim3(1, 384, 1), 256, 0, stream>>>(
        hb, FF, wt, c_b1, t128, 128, 0, 0);
    gemm_k<0><<<dim3(1, 768, 1), 256, 0, stream>>>(t128, 128, c_w2, 49, c_b2, out, 49, 49, 0, 0);
}